// Round 1
// baseline (4266.545 us; speedup 1.0000x reference)
//
#include <hip/hip_runtime.h>
#include <math.h>

#define NB 32
#define LSEQ 2048
#define DIN 64
#define NH 256
#define NN 32
#define NLAY 2
#define NCH 16
#define TCH 128   // LSEQ/NCH
#define ML1 350
#define ML2 400
#define MOUT 1024
#define LN_EPS 1e-5f

// ---------------- coefficient prep ----------------
__global__ void s4w_coef(const float* __restrict__ log_dt,
                         const float* __restrict__ C_re, const float* __restrict__ C_im,
                         const float* __restrict__ log_A_real, const float* __restrict__ A_imag,
                         float* __restrict__ ctr, float* __restrict__ cti,
                         float* __restrict__ er_, float* __restrict__ ei_,
                         float* __restrict__ pr_, float* __restrict__ pi_) {
    int idx = blockIdx.x * 256 + threadIdx.x;
    if (idx >= NLAY * NH * NN) return;
    int h = (idx / NN) % NH;
    int l = idx / (NN * NH);
    float dt = expf(log_dt[l * NH + h]);
    float ar = -expf(log_A_real[idx]);
    float ai = A_imag[idx];
    float dre = ar * dt, dim = ai * dt;
    float ex = expf(dre);
    float er = ex * cosf(dim);
    float ei = ex * sinf(dim);
    float den = ar * ar + ai * ai;
    float qr = ((er - 1.0f) * ar + ei * ai) / den;
    float qi = (ei * ar - (er - 1.0f) * ai) / den;
    float cr = C_re[idx], ci = C_im[idx];
    ctr[idx] = 2.0f * (cr * qr - ci * qi);
    cti[idx] = 2.0f * (cr * qi + ci * qr);
    er_[idx] = er; ei_[idx] = ei;
    // E^TCH in double for angle accuracy (angle up to ~1250 rad)
    double exT = exp((double)dre * (double)TCH);
    double ang = (double)dim * (double)TCH;
    pr_[idx] = (float)(exT * cos(ang));
    pi_[idx] = (float)(exT * sin(ang));
}

// ---------------- encoder: h[b,o,l] = sum_i x[b,l,i] w[o,i] + bias[o] ----------------
__global__ void s4w_enc(const float* __restrict__ x, const float* __restrict__ w,
                        const float* __restrict__ bias, float* __restrict__ hbuf) {
    int gid = blockIdx.x * 256 + threadIdx.x;       // (b,l) flat, 0..NB*LSEQ
    int b = gid / LSEQ, li = gid % LSEQ;
    int o0 = blockIdx.y * 64;
    float xr[DIN];
    const float4* xp = (const float4*)(x + (size_t)(b * LSEQ + li) * DIN);
#pragma unroll
    for (int i = 0; i < DIN / 4; i++) {
        float4 v = xp[i];
        xr[4 * i] = v.x; xr[4 * i + 1] = v.y; xr[4 * i + 2] = v.z; xr[4 * i + 3] = v.w;
    }
    for (int o = o0; o < o0 + 64; o++) {
        float acc = bias[o];
        const float* wp = w + o * DIN;
#pragma unroll
        for (int i = 0; i < DIN; i++) acc = fmaf(wp[i], xr[i], acc);
        hbuf[((size_t)b * NH + o) * LSEQ + li] = acc;
    }
}

// ---------------- conv phase A: per-chunk local end states ----------------
__global__ void s4w_convA(const float* __restrict__ hbuf,
                          const float* __restrict__ er_, const float* __restrict__ ei_,
                          float* __restrict__ states, int layer) {
    int h = blockIdx.x;
    int idx = blockIdx.y * 256 + threadIdx.x;   // 0..511 = b*NCH + c
    int b = idx / NCH, c = idx % NCH;
    __shared__ float es0[NN], es1[NN];
    if (threadIdx.x < NN) {
        int base = (layer * NH + h) * NN + threadIdx.x;
        es0[threadIdx.x] = er_[base];
        es1[threadIdx.x] = ei_[base];
    }
    __syncthreads();
    float er[NN], ei[NN], sr[NN], si[NN];
#pragma unroll
    for (int n = 0; n < NN; n++) { er[n] = es0[n]; ei[n] = es1[n]; sr[n] = 0.f; si[n] = 0.f; }
    const float4* up = (const float4*)(hbuf + ((size_t)b * NH + h) * LSEQ + c * TCH);
    for (int j4 = 0; j4 < TCH / 4; j4++) {
        float4 u4 = up[j4];
        float uu[4] = { u4.x, u4.y, u4.z, u4.w };
#pragma unroll
        for (int jj = 0; jj < 4; jj++) {
            float u = uu[jj];
#pragma unroll
            for (int n = 0; n < NN; n++) {
                float nsr = fmaf(er[n], sr[n], fmaf(-ei[n], si[n], u));
                float nsi = fmaf(er[n], si[n], ei[n] * sr[n]);
                sr[n] = nsr; si[n] = nsi;
            }
        }
    }
    float* sp = states + (size_t)((b * NH + h) * NCH + c) * NN * 2;
#pragma unroll
    for (int n = 0; n < NN; n++) { sp[2 * n] = sr[n]; sp[2 * n + 1] = si[n]; }
}

// ---------------- conv phase B: inter-chunk scan (in place: end -> start states) ----------------
__global__ void s4w_scan(float* __restrict__ states,
                         const float* __restrict__ pr_, const float* __restrict__ pi_, int layer) {
    int idx = blockIdx.x * 256 + threadIdx.x;  // b*NH*NN
    int n = idx % NN; int h = (idx / NN) % NH; int b = idx / (NN * NH);
    float pr = pr_[(layer * NH + h) * NN + n];
    float pi = pi_[(layer * NH + h) * NN + n];
    float sr = 0.f, si = 0.f;
    float* sp = states + (size_t)(b * NH + h) * NCH * NN * 2 + 2 * n;
    for (int c = 0; c < NCH; c++) {
        float e0 = sp[(size_t)c * NN * 2];
        float e1 = sp[(size_t)c * NN * 2 + 1];
        sp[(size_t)c * NN * 2] = sr;
        sp[(size_t)c * NN * 2 + 1] = si;
        float nsr = pr * sr - pi * si + e0;
        float nsi = pr * si + pi * sr + e1;
        sr = nsr; si = nsi;
    }
}

// ---------------- conv phase C: replay + Dp skip + exact GELU ----------------
__global__ void s4w_convC(const float* __restrict__ hbuf, float* __restrict__ ybuf,
                          const float* __restrict__ states,
                          const float* __restrict__ er_, const float* __restrict__ ei_,
                          const float* __restrict__ ctr_, const float* __restrict__ cti_,
                          const float* __restrict__ Dp, int layer) {
    int h = blockIdx.x;
    int idx = blockIdx.y * 256 + threadIdx.x;
    int b = idx / NCH, c = idx % NCH;
    __shared__ float es0[NN], es1[NN];
    __shared__ float2 cts[NN];
    if (threadIdx.x < NN) {
        int base = (layer * NH + h) * NN + threadIdx.x;
        es0[threadIdx.x] = er_[base];
        es1[threadIdx.x] = ei_[base];
        cts[threadIdx.x] = make_float2(ctr_[base], cti_[base]);
    }
    __syncthreads();
    float dp = Dp[layer * NH + h];
    float er[NN], ei[NN], sr[NN], si[NN];
    const float* sp = states + (size_t)((b * NH + h) * NCH + c) * NN * 2;
#pragma unroll
    for (int n = 0; n < NN; n++) {
        er[n] = es0[n]; ei[n] = es1[n];
        sr[n] = sp[2 * n]; si[n] = sp[2 * n + 1];
    }
    const float4* up = (const float4*)(hbuf + ((size_t)b * NH + h) * LSEQ + c * TCH);
    float4* yp = (float4*)(ybuf + ((size_t)b * NH + h) * LSEQ + c * TCH);
    for (int j4 = 0; j4 < TCH / 4; j4++) {
        float4 u4 = up[j4];
        float uu[4] = { u4.x, u4.y, u4.z, u4.w };
        float oo[4];
#pragma unroll
        for (int jj = 0; jj < 4; jj++) {
            float u = uu[jj];
            float a0 = 0.f, a1 = 0.f, a2 = 0.f, a3 = 0.f;
#pragma unroll
            for (int n = 0; n < NN; n++) {
                float nsr = fmaf(er[n], sr[n], fmaf(-ei[n], si[n], u));
                float nsi = fmaf(er[n], si[n], ei[n] * sr[n]);
                sr[n] = nsr; si[n] = nsi;
                float2 ct = cts[n];
                if ((n & 3) == 0)      { a0 = fmaf(ct.x, nsr, a0); a0 = fmaf(-ct.y, nsi, a0); }
                else if ((n & 3) == 1) { a1 = fmaf(ct.x, nsr, a1); a1 = fmaf(-ct.y, nsi, a1); }
                else if ((n & 3) == 2) { a2 = fmaf(ct.x, nsr, a2); a2 = fmaf(-ct.y, nsi, a2); }
                else                   { a3 = fmaf(ct.x, nsr, a3); a3 = fmaf(-ct.y, nsi, a3); }
            }
            float yv = (a0 + a1) + (a2 + a3);
            yv = fmaf(u, dp, yv);
            // exact GELU
            float g = 0.5f * yv * (1.0f + erff(yv * 0.70710678118f));
            oo[jj] = g;
        }
        yp[j4] = make_float4(oo[0], oo[1], oo[2], oo[3]);
    }
}

// ---------------- transpose out_w to K-major ----------------
__global__ void s4w_trow(const float* __restrict__ ow, float* __restrict__ owT, int layer) {
    int idx = blockIdx.x * 256 + threadIdx.x;   // 512*256
    int o = idx / NH, k = idx % NH;
    owT[k * 2 * NH + o] = ow[(size_t)layer * 2 * NH * NH + o * NH + k];
}

// ---------------- proj GEMM + GLU + residual + channel-LN (in-place h update) ----------------
__global__ void s4w_proj(const float* __restrict__ ybuf, float* __restrict__ hbuf,
                         const float* __restrict__ owT, const float* __restrict__ ob,
                         const float* __restrict__ lnw, const float* __restrict__ lnb, int layer) {
    int b = blockIdx.x / (LSEQ / 16);
    int l0 = (blockIdx.x % (LSEQ / 16)) * 16;
    int t = threadIdx.x;
    __shared__ __align__(16) float ys[NH][16];
    __shared__ float ps[256], pq[256];
    __shared__ float mean_s[16], inv_s[16];

    // stage y tile: thread t loads row t (64B contiguous)
    {
        const float4* yp = (const float4*)(ybuf + ((size_t)b * NH + t) * LSEQ + l0);
        float4* dst = (float4*)&ys[t][0];
        dst[0] = yp[0]; dst[1] = yp[1]; dst[2] = yp[2]; dst[3] = yp[3];
    }
    __syncthreads();

    float acca[16], accg[16];
#pragma unroll
    for (int i = 0; i < 16; i++) { acca[i] = 0.f; accg[i] = 0.f; }

    for (int k = 0; k < NH; k++) {
        float wa = owT[k * 2 * NH + t];
        float wg = owT[k * 2 * NH + NH + t];
        const float4* yr = (const float4*)&ys[k][0];
        float4 y0 = yr[0], y1 = yr[1], y2 = yr[2], y3 = yr[3];
        float yv[16] = { y0.x, y0.y, y0.z, y0.w, y1.x, y1.y, y1.z, y1.w,
                         y2.x, y2.y, y2.z, y2.w, y3.x, y3.y, y3.z, y3.w };
#pragma unroll
        for (int lc = 0; lc < 16; lc++) {
            acca[lc] = fmaf(wa, yv[lc], acca[lc]);
            accg[lc] = fmaf(wg, yv[lc], accg[lc]);
        }
    }

    // epilogue: bias + GLU + residual
    float ob0 = ob[layer * 2 * NH + t];
    float ob1 = ob[layer * 2 * NH + NH + t];
    float hres[16];
    {
        const float4* hp = (const float4*)(hbuf + ((size_t)b * NH + t) * LSEQ + l0);
        float4 h0 = hp[0], h1 = hp[1], h2 = hp[2], h3 = hp[3];
        float tmp[16] = { h0.x, h0.y, h0.z, h0.w, h1.x, h1.y, h1.z, h1.w,
                          h2.x, h2.y, h2.z, h2.w, h3.x, h3.y, h3.z, h3.w };
#pragma unroll
        for (int i = 0; i < 16; i++) hres[i] = tmp[i];
    }
    float r[16];
#pragma unroll
    for (int lc = 0; lc < 16; lc++) {
        float a = acca[lc] + ob0;
        float g = accg[lc] + ob1;
        float v = a * (1.0f / (1.0f + expf(-g)));
        r[lc] = v + hres[lc];
    }

    // channel LayerNorm over t (H=256) for each of the 16 columns
    __syncthreads();                     // all k-loop reads of ys done
#pragma unroll
    for (int lc = 0; lc < 16; lc++) ys[t][lc] = r[lc];
    __syncthreads();
    {
        int col = t & 15, rp = t >> 4;
        float s = 0.f, q = 0.f;
#pragma unroll
        for (int i = 0; i < 16; i++) {
            float v = ys[rp * 16 + i][col];
            s += v; q = fmaf(v, v, q);
        }
        ps[t] = s; pq[t] = q;
    }
    __syncthreads();
    if (t < 16) {
        float S = 0.f, Q = 0.f;
#pragma unroll
        for (int i = 0; i < 16; i++) { S += ps[t + 16 * i]; Q += pq[t + 16 * i]; }
        float m = S / (float)NH;
        float v = Q / (float)NH - m * m;
        mean_s[t] = m;
        inv_s[t] = rsqrtf(v + LN_EPS);
    }
    __syncthreads();
    float lw = lnw[layer * NH + t], lb = lnb[layer * NH + t];
    float outv[16];
#pragma unroll
    for (int lc = 0; lc < 16; lc++)
        outv[lc] = (r[lc] - mean_s[lc]) * inv_s[lc] * lw + lb;
    float4* op = (float4*)(hbuf + ((size_t)b * NH + t) * LSEQ + l0);
    op[0] = make_float4(outv[0], outv[1], outv[2], outv[3]);
    op[1] = make_float4(outv[4], outv[5], outv[6], outv[7]);
    op[2] = make_float4(outv[8], outv[9], outv[10], outv[11]);
    op[3] = make_float4(outv[12], outv[13], outv[14], outv[15]);
}

// ---------------- gather last timestep ----------------
__global__ void s4w_gather(const float* __restrict__ hbuf, float* __restrict__ hl) {
    int idx = blockIdx.x * 256 + threadIdx.x;   // b*NH
    int b = idx / NH, t = idx % NH;
    hl[idx] = hbuf[((size_t)b * NH + t) * LSEQ + LSEQ - 1];
}

// ---------------- small MLP layer ----------------
__global__ void s4w_mlp(const float* __restrict__ in, const float* __restrict__ w,
                        const float* __restrict__ bias, float* __restrict__ out,
                        int K, int N, int do_relu) {
    int idx = blockIdx.x * 256 + threadIdx.x;
    if (idx >= NB * N) return;
    int b = idx / N, o = idx % N;
    const float* ip = in + (size_t)b * K;
    const float* wp = w + (size_t)o * K;
    float acc = bias[o];
    for (int k = 0; k < K; k++) acc = fmaf(ip[k], wp[k], acc);
    if (do_relu) acc = fmaxf(acc, 0.f);
    out[idx] = acc;
}

extern "C" void kernel_launch(void* const* d_in, const int* in_sizes, int n_in,
                              void* d_out, int out_size, void* d_ws, size_t ws_size,
                              hipStream_t stream) {
    const float* x          = (const float*)d_in[0];
    const float* enc_w      = (const float*)d_in[1];
    const float* enc_b      = (const float*)d_in[2];
    const float* log_dt     = (const float*)d_in[3];
    const float* C_re       = (const float*)d_in[4];
    const float* C_im       = (const float*)d_in[5];
    const float* log_A_real = (const float*)d_in[6];
    const float* A_imag     = (const float*)d_in[7];
    const float* Dp         = (const float*)d_in[8];
    const float* out_w      = (const float*)d_in[9];
    const float* out_b      = (const float*)d_in[10];
    const float* ln_w       = (const float*)d_in[11];
    const float* ln_b       = (const float*)d_in[12];
    const float* lin1_w     = (const float*)d_in[13];
    const float* lin1_b     = (const float*)d_in[14];
    const float* lin2_w     = (const float*)d_in[15];
    const float* lin2_b     = (const float*)d_in[16];
    const float* lin3_w     = (const float*)d_in[17];
    const float* lin3_b     = (const float*)d_in[18];
    float* outp = (float*)d_out;

    float* ws = (float*)d_ws;
    size_t off = 0;
    float* hbuf   = ws + off; off += (size_t)NB * NH * LSEQ;           // 16.78M
    float* ybuf   = ws + off; off += (size_t)NB * NH * LSEQ;           // 16.78M
    float* states = ws + off; off += (size_t)NB * NH * NCH * NN * 2;   // 8.39M
    float* ctr    = ws + off; off += NLAY * NH * NN;
    float* cti    = ws + off; off += NLAY * NH * NN;
    float* er_    = ws + off; off += NLAY * NH * NN;
    float* ei_    = ws + off; off += NLAY * NH * NN;
    float* pr_    = ws + off; off += NLAY * NH * NN;
    float* pi_    = ws + off; off += NLAY * NH * NN;
    float* owT    = ws + off; off += 2 * NH * NH;
    float* hl     = ws + off; off += NB * NH;
    float* t1     = ws + off; off += NB * ML1;
    float* t2     = ws + off; off += NB * ML2;

    s4w_coef<<<(NLAY * NH * NN + 255) / 256, 256, 0, stream>>>(
        log_dt, C_re, C_im, log_A_real, A_imag, ctr, cti, er_, ei_, pr_, pi_);

    s4w_enc<<<dim3(NB * LSEQ / 256, 4), 256, 0, stream>>>(x, enc_w, enc_b, hbuf);

    for (int layer = 0; layer < NLAY; layer++) {
        s4w_convA<<<dim3(NH, 2), 256, 0, stream>>>(hbuf, er_, ei_, states, layer);
        s4w_scan<<<(NB * NH * NN) / 256, 256, 0, stream>>>(states, pr_, pi_, layer);
        s4w_convC<<<dim3(NH, 2), 256, 0, stream>>>(hbuf, ybuf, states, er_, ei_, ctr, cti, Dp, layer);
        s4w_trow<<<(2 * NH * NH) / 256, 256, 0, stream>>>(out_w, owT, layer);
        s4w_proj<<<NB * (LSEQ / 16), 256, 0, stream>>>(ybuf, hbuf, owT, out_b, ln_w, ln_b, layer);
    }

    s4w_gather<<<(NB * NH) / 256, 256, 0, stream>>>(hbuf, hl);
    s4w_mlp<<<(NB * ML1 + 255) / 256, 256, 0, stream>>>(hl, lin1_w, lin1_b, t1, NH, ML1, 1);
    s4w_mlp<<<(NB * ML2 + 255) / 256, 256, 0, stream>>>(t1, lin2_w, lin2_b, t2, ML1, ML2, 1);
    s4w_mlp<<<(NB * MOUT + 255) / 256, 256, 0, stream>>>(t2, lin3_w, lin3_b, outp, ML2, MOUT, 0);
}